// Round 1
// baseline (137.306 us; speedup 1.0000x reference)
//
#include <hip/hip_runtime.h>

typedef float f32x4 __attribute__((ext_vector_type(4)));
typedef __bf16 bf16x8 __attribute__((ext_vector_type(8)));
typedef unsigned short ushort_t;

#define NEGV (-100000.0f)

constexpr int Bb = 8, Ss = 2048, Ee = 1024, Hh = 64;

static __device__ __forceinline__ ushort_t f2bfu(float f) {
  return __builtin_bit_cast(ushort_t, (__bf16)f);
}
static __device__ __forceinline__ f32x4 mfma16(bf16x8 a, bf16x8 b, f32x4 c) {
  return __builtin_amdgcn_mfma_f32_16x16x32_bf16(a, b, c, 0, 0, 0);
}

// ---------------- weight transpose + bf16 convert: Wt[m][h][e] ----------------
__global__ __launch_bounds__(256) void k_wtrans(const float* __restrict__ Wq,
                                                const float* __restrict__ Wk,
                                                const float* __restrict__ Wv,
                                                ushort_t* __restrict__ Wt) {
  __shared__ float tile[64][65];
  const float* W = (blockIdx.y == 0) ? Wq : (blockIdx.y == 1 ? Wk : Wv);
  int kt = blockIdx.x, t = threadIdx.x;
  int r = t >> 2, cq = t & 3;
  const float* src = W + (kt * 64 + r) * Hh + cq * 16;
#pragma unroll
  for (int j = 0; j < 16; j += 4) {
    float4 v = *reinterpret_cast<const float4*>(src + j);
    tile[r][cq * 16 + j + 0] = v.x;
    tile[r][cq * 16 + j + 1] = v.y;
    tile[r][cq * 16 + j + 2] = v.z;
    tile[r][cq * 16 + j + 3] = v.w;
  }
  __syncthreads();
  int n = t >> 2, kq = t & 3;
  ushort_t ob[16];
#pragma unroll
  for (int j = 0; j < 16; ++j) ob[j] = f2bfu(tile[kq * 16 + j][n]);
  ushort_t* dst = Wt + ((size_t)blockIdx.y * 64 + n) * Ee + kt * 64 + kq * 16;
  reinterpret_cast<uint4*>(dst)[0] = reinterpret_cast<uint4*>(ob)[0];
  reinterpret_cast<uint4*>(dst)[1] = reinterpret_cast<uint4*>(ob)[1];
}

// ---------------- fused QKV projection ----------------
// q (pre-scaled by 1/8) and k stored [B*S][64] bf16; v stored transposed vt[b][h][s] bf16.
__global__ __launch_bounds__(256) void k_proj(const float* __restrict__ hs,
                                              const float* __restrict__ bq,
                                              const float* __restrict__ bk,
                                              const float* __restrict__ bv,
                                              const ushort_t* __restrict__ Wt,
                                              ushort_t* __restrict__ q,
                                              ushort_t* __restrict__ k,
                                              ushort_t* __restrict__ vt) {
  int t = threadIdx.x, w = t >> 6, l = t & 63, g = l >> 4, c = l & 15;
  int arow = blockIdx.x * 64 + w * 16 + c;
  const float* ap = hs + (size_t)arow * Ee + g * 8;

  f32x4 acc[3][4];
#pragma unroll
  for (int m = 0; m < 3; ++m)
#pragma unroll
    for (int nt = 0; nt < 4; ++nt) acc[m][nt] = f32x4{0.f, 0.f, 0.f, 0.f};

  for (int kk = 0; kk < Ee; kk += 64) {
    bf16x8 af[2];
#pragma unroll
    for (int ks = 0; ks < 2; ++ks) {
      float4 f0 = *reinterpret_cast<const float4*>(ap + kk + ks * 32);
      float4 f1 = *reinterpret_cast<const float4*>(ap + kk + ks * 32 + 4);
      bf16x8 a;
      a[0] = (__bf16)f0.x; a[1] = (__bf16)f0.y; a[2] = (__bf16)f0.z; a[3] = (__bf16)f0.w;
      a[4] = (__bf16)f1.x; a[5] = (__bf16)f1.y; a[6] = (__bf16)f1.z; a[7] = (__bf16)f1.w;
      af[ks] = a;
    }
#pragma unroll
    for (int m = 0; m < 3; ++m) {
      const ushort_t* wp = Wt + ((size_t)(m * 64 + c)) * Ee + kk + g * 8;
#pragma unroll
      for (int nt = 0; nt < 4; ++nt) {
        bf16x8 b0 = *reinterpret_cast<const bf16x8*>(wp + (size_t)nt * 16 * Ee);
        bf16x8 b1 = *reinterpret_cast<const bf16x8*>(wp + (size_t)nt * 16 * Ee + 32);
        acc[m][nt] = mfma16(af[0], b0, acc[m][nt]);
        acc[m][nt] = mfma16(af[1], b1, acc[m][nt]);
      }
    }
  }

  int orow = blockIdx.x * 64 + w * 16 + g * 4;
#pragma unroll
  for (int m = 0; m < 3; ++m) {
    const float* bias = (m == 0) ? bq : ((m == 1) ? bk : bv);
#pragma unroll
    for (int nt = 0; nt < 4; ++nt) {
      int h = nt * 16 + c;
      float bb = bias[h];
#pragma unroll
      for (int i = 0; i < 4; ++i) {
        int row = orow + i;
        float val = acc[m][nt][i] + bb;
        if (m == 0) {
          q[(size_t)row * Hh + h] = f2bfu(val * 0.125f);
        } else if (m == 1) {
          k[(size_t)row * Hh + h] = f2bfu(val);
        } else {
          int bi = row >> 11, s2 = row & 2047;
          vt[((size_t)(bi * 64 + h)) * Ss + s2] = f2bfu(val);
        }
      }
    }
  }
}

// ---------------- fused masked flash attention ----------------
// Block: 16 q-rows of one batch; 4 waves split the 2048-key range (512 each);
// LDS combine of (m, l, O) partials at the end.
__global__ __launch_bounds__(256, 2) void k_attn(const ushort_t* __restrict__ qs,
                                                 const ushort_t* __restrict__ km,
                                                 const ushort_t* __restrict__ vt,
                                                 const int* __restrict__ am,
                                                 float* __restrict__ out) {
  __shared__ __align__(16) ushort_t plds[4][16][72];  // per-wave P tile, stride 144B (16B aligned)
  __shared__ float obuf[4][16][64];
  __shared__ float mb[4][16], lb[4][16];

  int t = threadIdx.x, w = t >> 6, l = t & 63, g = l >> 4, c = l & 15;
  int b = blockIdx.y;
  int q0 = blockIdx.x * 16;

  // Q A-fragments, hoisted for the whole KV loop
  const ushort_t* qp = qs + ((size_t)(b * Ss + q0 + c)) * Hh + g * 8;
  bf16x8 qa0 = *reinterpret_cast<const bf16x8*>(qp);
  bf16x8 qa1 = *reinterpret_cast<const bf16x8*>(qp + 32);

  int mq[4], qi[4];
#pragma unroll
  for (int i = 0; i < 4; ++i) {
    qi[i] = q0 + g * 4 + i;
    mq[i] = am[b * Ss + qi[i]];
  }

  float mi[4], li[4];
  f32x4 o[4];
#pragma unroll
  for (int i = 0; i < 4; ++i) { mi[i] = -1e30f; li[i] = 0.f; }
#pragma unroll
  for (int ht = 0; ht < 4; ++ht) o[ht] = f32x4{0.f, 0.f, 0.f, 0.f};

  const int kvbeg = w * 512, kvend = kvbeg + 512;
  for (int kv = kvbeg; kv < kvend; kv += 64) {
    // ---- scores: S[16q][64k] per wave ----
    f32x4 sc[4];
#pragma unroll
    for (int nt = 0; nt < 4; ++nt) {
      const ushort_t* kp = km + ((size_t)(b * Ss + kv + nt * 16 + c)) * Hh + g * 8;
      bf16x8 k0 = *reinterpret_cast<const bf16x8*>(kp);
      bf16x8 k1 = *reinterpret_cast<const bf16x8*>(kp + 32);
      f32x4 z = {0.f, 0.f, 0.f, 0.f};
      sc[nt] = mfma16(qa0, k0, z);
      sc[nt] = mfma16(qa1, k1, sc[nt]);
    }
    // ---- mask: allowed = (mq&mk&(q>=k)) | (!mq&!mk) ----
#pragma unroll
    for (int nt = 0; nt < 4; ++nt) {
      int kidx = kv + nt * 16 + c;
      int mk = am[b * Ss + kidx];
#pragma unroll
      for (int i = 0; i < 4; ++i) {
        bool allowed = mq[i] ? (mk && (qi[i] >= kidx)) : (!mk);
        sc[nt][i] += allowed ? 0.f : NEGV;
      }
    }
    // ---- online softmax (row = reduce over c lanes) ----
    float tm[4], al[4], rs[4];
#pragma unroll
    for (int i = 0; i < 4; ++i)
      tm[i] = fmaxf(fmaxf(sc[0][i], sc[1][i]), fmaxf(sc[2][i], sc[3][i]));
#pragma unroll
    for (int d = 1; d < 16; d <<= 1)
#pragma unroll
      for (int i = 0; i < 4; ++i) tm[i] = fmaxf(tm[i], __shfl_xor(tm[i], d));
#pragma unroll
    for (int i = 0; i < 4; ++i) {
      float mn = fmaxf(mi[i], tm[i]);
      al[i] = __expf(mi[i] - mn);
      mi[i] = mn;
      rs[i] = 0.f;
    }
#pragma unroll
    for (int nt = 0; nt < 4; ++nt)
#pragma unroll
      for (int i = 0; i < 4; ++i) {
        float p = __expf(sc[nt][i] - mi[i]);
        sc[nt][i] = p;
        rs[i] += p;
      }
#pragma unroll
    for (int d = 1; d < 16; d <<= 1)
#pragma unroll
      for (int i = 0; i < 4; ++i) rs[i] += __shfl_xor(rs[i], d);
#pragma unroll
    for (int i = 0; i < 4; ++i) li[i] = li[i] * al[i] + rs[i];
#pragma unroll
    for (int ht = 0; ht < 4; ++ht)
#pragma unroll
      for (int i = 0; i < 4; ++i) o[ht][i] *= al[i];

    // ---- P -> LDS (bf16), transpose C-layout -> A-frag layout ----
#pragma unroll
    for (int nt = 0; nt < 4; ++nt)
#pragma unroll
      for (int i = 0; i < 4; ++i) plds[w][g * 4 + i][nt * 16 + c] = f2bfu(sc[nt][i]);
    asm volatile("s_waitcnt lgkmcnt(0)" ::: "memory");
    bf16x8 pa0 = *reinterpret_cast<const bf16x8*>(&plds[w][c][g * 8]);
    bf16x8 pa1 = *reinterpret_cast<const bf16x8*>(&plds[w][c][32 + g * 8]);

    // ---- PV ----
#pragma unroll
    for (int ht = 0; ht < 4; ++ht) {
      const ushort_t* vp = vt + ((size_t)(b * 64 + ht * 16 + c)) * Ss + kv + g * 8;
      bf16x8 v0 = *reinterpret_cast<const bf16x8*>(vp);
      bf16x8 v1 = *reinterpret_cast<const bf16x8*>(vp + 32);
      o[ht] = mfma16(pa0, v0, o[ht]);
      o[ht] = mfma16(pa1, v1, o[ht]);
    }
  }

  // ---- combine the 4 KV-split partials ----
  if (c == 0) {
#pragma unroll
    for (int i = 0; i < 4; ++i) {
      mb[w][g * 4 + i] = mi[i];
      lb[w][g * 4 + i] = li[i];
    }
  }
#pragma unroll
  for (int ht = 0; ht < 4; ++ht)
#pragma unroll
    for (int i = 0; i < 4; ++i) obuf[w][g * 4 + i][ht * 16 + c] = o[ht][i];
  __syncthreads();

  int row = t >> 4, hq = t & 15;
  float mg = fmaxf(fmaxf(mb[0][row], mb[1][row]), fmaxf(mb[2][row], mb[3][row]));
  float lg = 0.f, sw[4];
#pragma unroll
  for (int w2 = 0; w2 < 4; ++w2) {
    sw[w2] = __expf(mb[w2][row] - mg);
    lg += lb[w2][row] * sw[w2];
  }
  float4 ov = {0.f, 0.f, 0.f, 0.f};
#pragma unroll
  for (int w2 = 0; w2 < 4; ++w2) {
    float4 ob = *reinterpret_cast<const float4*>(&obuf[w2][row][hq * 4]);
    ov.x += ob.x * sw[w2]; ov.y += ob.y * sw[w2];
    ov.z += ob.z * sw[w2]; ov.w += ob.w * sw[w2];
  }
  float inv = 1.f / lg;
  float4 res = {ov.x * inv, ov.y * inv, ov.z * inv, ov.w * inv};
  *reinterpret_cast<float4*>(out + ((size_t)(b * Ss + q0 + row)) * Hh + hq * 4) = res;
}

extern "C" void kernel_launch(void* const* d_in, const int* in_sizes, int n_in,
                              void* d_out, int out_size, void* d_ws, size_t ws_size,
                              hipStream_t stream) {
  const float* hs = (const float*)d_in[0];
  const int* am = (const int*)d_in[1];
  const float* Wq = (const float*)d_in[2];
  const float* bq = (const float*)d_in[3];
  const float* Wk = (const float*)d_in[4];
  const float* bk = (const float*)d_in[5];
  const float* Wv = (const float*)d_in[6];
  const float* bv = (const float*)d_in[7];
  float* out = (float*)d_out;

  char* ws = (char*)d_ws;
  ushort_t* qsp = (ushort_t*)(ws + 0);                // 2 MB: [B*S][64] bf16, pre-scaled
  ushort_t* kp = (ushort_t*)(ws + (2u << 20));        // 2 MB: [B*S][64] bf16
  ushort_t* vtp = (ushort_t*)(ws + (4u << 20));       // 2 MB: [B][64][S] bf16 (V^T)
  ushort_t* wtp = (ushort_t*)(ws + (6u << 20));       // 384 KB: [3][64][1024] bf16 (W^T)

  k_wtrans<<<dim3(16, 3), 256, 0, stream>>>(Wq, Wk, Wv, wtp);
  k_proj<<<dim3(256), 256, 0, stream>>>(hs, bq, bk, bv, wtp, qsp, kp, vtp);
  k_attn<<<dim3(128, 8), 256, 0, stream>>>(qsp, kp, vtp, am, out);
}

// Round 2
// 124.580 us; speedup vs baseline: 1.1021x; 1.1021x over previous
//
#include <hip/hip_runtime.h>

typedef float f32x4 __attribute__((ext_vector_type(4)));
typedef __bf16 bf16x8 __attribute__((ext_vector_type(8)));
typedef unsigned short ushort_t;

#define NEGV (-100000.0f)

constexpr int Bb = 8, Ss = 2048, Ee = 1024, Hh = 64;

static __device__ __forceinline__ ushort_t f2bfu(float f) {
  return __builtin_bit_cast(ushort_t, (__bf16)f);
}
static __device__ __forceinline__ f32x4 mfma16(bf16x8 a, bf16x8 b, f32x4 c) {
  return __builtin_amdgcn_mfma_f32_16x16x32_bf16(a, b, c, 0, 0, 0);
}

// ---------------- weight transpose + bf16 convert: Wt[m][h][e] ----------------
__global__ __launch_bounds__(256) void k_wtrans(const float* __restrict__ Wq,
                                                const float* __restrict__ Wk,
                                                const float* __restrict__ Wv,
                                                ushort_t* __restrict__ Wt) {
  __shared__ float tile[64][65];
  const float* W = (blockIdx.y == 0) ? Wq : (blockIdx.y == 1 ? Wk : Wv);
  int kt = blockIdx.x, t = threadIdx.x;
  int r = t >> 2, cq = t & 3;
  const float* src = W + (kt * 64 + r) * Hh + cq * 16;
#pragma unroll
  for (int j = 0; j < 16; j += 4) {
    float4 v = *reinterpret_cast<const float4*>(src + j);
    tile[r][cq * 16 + j + 0] = v.x;
    tile[r][cq * 16 + j + 1] = v.y;
    tile[r][cq * 16 + j + 2] = v.z;
    tile[r][cq * 16 + j + 3] = v.w;
  }
  __syncthreads();
  int n = t >> 2, kq = t & 3;
  ushort_t ob[16];
#pragma unroll
  for (int j = 0; j < 16; ++j) ob[j] = f2bfu(tile[kq * 16 + j][n]);
  ushort_t* dst = Wt + ((size_t)blockIdx.y * 64 + n) * Ee + kt * 64 + kq * 16;
  reinterpret_cast<uint4*>(dst)[0] = reinterpret_cast<uint4*>(ob)[0];
  reinterpret_cast<uint4*>(dst)[1] = reinterpret_cast<uint4*>(ob)[1];
}

// ---------------- fused QKV projection, K-split by 4 waves ----------------
// Block: 16 rows, wave w covers K in [w*256, w*256+256). Two-stage LDS reduce.
// q pre-scaled by 1/8; q,k stored [B*S][64] bf16; v stored transposed vt[b][h][s].
__global__ __launch_bounds__(256, 3) void k_proj(const float* __restrict__ hs,
                                                 const float* __restrict__ bq,
                                                 const float* __restrict__ bk,
                                                 const float* __restrict__ bv,
                                                 const ushort_t* __restrict__ Wt,
                                                 ushort_t* __restrict__ q,
                                                 ushort_t* __restrict__ k,
                                                 ushort_t* __restrict__ vt) {
  __shared__ float obuf[2][16][196];  // stride 196 words: rows g*4 apart land 16 banks apart
  int t = threadIdx.x, w = t >> 6, l = t & 63, g = l >> 4, c = l & 15;
  int row0 = blockIdx.x * 16;
  const int k0 = w * 256;
  const float* ap = hs + (size_t)(row0 + c) * Ee + k0 + g * 8;

  f32x4 acc[3][4];
#pragma unroll
  for (int m = 0; m < 3; ++m)
#pragma unroll
    for (int nt = 0; nt < 4; ++nt) acc[m][nt] = f32x4{0.f, 0.f, 0.f, 0.f};

#pragma unroll
  for (int kk = 0; kk < 256; kk += 64) {
    bf16x8 af[2];
#pragma unroll
    for (int ks = 0; ks < 2; ++ks) {
      float4 f0 = *reinterpret_cast<const float4*>(ap + kk + ks * 32);
      float4 f1 = *reinterpret_cast<const float4*>(ap + kk + ks * 32 + 4);
      bf16x8 a;
      a[0] = (__bf16)f0.x; a[1] = (__bf16)f0.y; a[2] = (__bf16)f0.z; a[3] = (__bf16)f0.w;
      a[4] = (__bf16)f1.x; a[5] = (__bf16)f1.y; a[6] = (__bf16)f1.z; a[7] = (__bf16)f1.w;
      af[ks] = a;
    }
#pragma unroll
    for (int m = 0; m < 3; ++m) {
      const ushort_t* wp = Wt + ((size_t)(m * 64 + c)) * Ee + k0 + kk + g * 8;
#pragma unroll
      for (int nt = 0; nt < 4; ++nt) {
        bf16x8 b0 = *reinterpret_cast<const bf16x8*>(wp + (size_t)nt * 16 * Ee);
        bf16x8 b1 = *reinterpret_cast<const bf16x8*>(wp + (size_t)nt * 16 * Ee + 32);
        acc[m][nt] = mfma16(af[0], b0, acc[m][nt]);
        acc[m][nt] = mfma16(af[1], b1, acc[m][nt]);
      }
    }
  }

  // two-stage cross-wave reduction
  if (w >= 2) {
#pragma unroll
    for (int m = 0; m < 3; ++m)
#pragma unroll
      for (int nt = 0; nt < 4; ++nt)
#pragma unroll
        for (int i = 0; i < 4; ++i)
          obuf[w - 2][g * 4 + i][m * 64 + nt * 16 + c] = acc[m][nt][i];
  }
  __syncthreads();
  if (w < 2) {
#pragma unroll
    for (int m = 0; m < 3; ++m)
#pragma unroll
      for (int nt = 0; nt < 4; ++nt)
#pragma unroll
        for (int i = 0; i < 4; ++i)
          acc[m][nt][i] += obuf[w][g * 4 + i][m * 64 + nt * 16 + c];
    __builtin_amdgcn_s_waitcnt(0);  // ensure reads done before overwrite below
#pragma unroll
    for (int m = 0; m < 3; ++m)
#pragma unroll
      for (int nt = 0; nt < 4; ++nt)
#pragma unroll
        for (int i = 0; i < 4; ++i)
          obuf[w][g * 4 + i][m * 64 + nt * 16 + c] = acc[m][nt][i];
  }
  __syncthreads();

  // final combine + bias + convert + store: thread t -> row r, float4-col f
  int r = t >> 4, f = t & 15;
  int grow = row0 + r;
#pragma unroll
  for (int m = 0; m < 3; ++m) {
    float4 v0 = *reinterpret_cast<const float4*>(&obuf[0][r][m * 64 + f * 4]);
    float4 v1 = *reinterpret_cast<const float4*>(&obuf[1][r][m * 64 + f * 4]);
    const float* bias = (m == 0) ? bq : ((m == 1) ? bk : bv);
    float4 bb = *reinterpret_cast<const float4*>(bias + f * 4);
    float vals[4] = {v0.x + v1.x + bb.x, v0.y + v1.y + bb.y,
                     v0.z + v1.z + bb.z, v0.w + v1.w + bb.w};
    if (m == 0) {
      ushort_t ob[4];
#pragma unroll
      for (int j = 0; j < 4; ++j) ob[j] = f2bfu(vals[j] * 0.125f);
      *reinterpret_cast<uint2*>(q + (size_t)grow * Hh + f * 4) = *reinterpret_cast<uint2*>(ob);
    } else if (m == 1) {
      ushort_t ob[4];
#pragma unroll
      for (int j = 0; j < 4; ++j) ob[j] = f2bfu(vals[j]);
      *reinterpret_cast<uint2*>(k + (size_t)grow * Hh + f * 4) = *reinterpret_cast<uint2*>(ob);
    } else {
      int bi = grow >> 11, s2 = grow & 2047;
#pragma unroll
      for (int j = 0; j < 4; ++j)
        vt[((size_t)(bi * 64 + f * 4 + j)) * Ss + s2] = f2bfu(vals[j]);
    }
  }
}

// ---------------- fused masked flash attention, software-pipelined ----------------
// Block: 16 q-rows of one batch; 4 waves split the 2048-key range (512 each);
// K-frags+masks double-buffered in registers, V issued at iteration top, so the
// LDS-transpose fence no longer serializes global loads. LDS combine at end.
struct KT {
  bf16x8 a0[4], a1[4];
  int mk[4];
};

__global__ __launch_bounds__(256, 2) void k_attn(const ushort_t* __restrict__ qs,
                                                 const ushort_t* __restrict__ km,
                                                 const ushort_t* __restrict__ vt,
                                                 const int* __restrict__ am,
                                                 float* __restrict__ out) {
  __shared__ __align__(16) ushort_t plds[4][16][72];  // per-wave P tile, stride 144B
  __shared__ float obuf[4][16][64];
  __shared__ float mb[4][16], lb[4][16];

  int t = threadIdx.x, w = t >> 6, l = t & 63, g = l >> 4, c = l & 15;
  int b = blockIdx.y;
  int q0 = blockIdx.x * 16;

  const ushort_t* qp = qs + ((size_t)(b * Ss + q0 + c)) * Hh + g * 8;
  bf16x8 qa0 = *reinterpret_cast<const bf16x8*>(qp);
  bf16x8 qa1 = *reinterpret_cast<const bf16x8*>(qp + 32);

  int mq[4], qi[4];
#pragma unroll
  for (int i = 0; i < 4; ++i) {
    qi[i] = q0 + g * 4 + i;
    mq[i] = am[b * Ss + qi[i]];
  }

  float mi[4], li[4];
  f32x4 o[4];
#pragma unroll
  for (int i = 0; i < 4; ++i) { mi[i] = -1e30f; li[i] = 0.f; }
#pragma unroll
  for (int ht = 0; ht < 4; ++ht) o[ht] = f32x4{0.f, 0.f, 0.f, 0.f};

  const int kvbeg = w * 512, kvend = kvbeg + 512;

  auto loadK = [&](int kv, KT& kt) {
#pragma unroll
    for (int nt = 0; nt < 4; ++nt) {
      const ushort_t* kp = km + ((size_t)(b * Ss + kv + nt * 16 + c)) * Hh + g * 8;
      kt.a0[nt] = *reinterpret_cast<const bf16x8*>(kp);
      kt.a1[nt] = *reinterpret_cast<const bf16x8*>(kp + 32);
      kt.mk[nt] = am[b * Ss + kv + nt * 16 + c];
    }
  };
  auto loadV = [&](int kv, bf16x8* v0, bf16x8* v1) {
#pragma unroll
    for (int ht = 0; ht < 4; ++ht) {
      const ushort_t* vp = vt + ((size_t)(b * 64 + ht * 16 + c)) * Ss + kv + g * 8;
      v0[ht] = *reinterpret_cast<const bf16x8*>(vp);
      v1[ht] = *reinterpret_cast<const bf16x8*>(vp + 32);
    }
  };

  auto body = [&](int kv, KT& kt, bf16x8* v0, bf16x8* v1) {
    // ---- scores ----
    f32x4 sc[4];
    __builtin_amdgcn_s_setprio(1);
#pragma unroll
    for (int nt = 0; nt < 4; ++nt) {
      f32x4 z = {0.f, 0.f, 0.f, 0.f};
      sc[nt] = mfma16(qa0, kt.a0[nt], z);
      sc[nt] = mfma16(qa1, kt.a1[nt], sc[nt]);
    }
    __builtin_amdgcn_s_setprio(0);
    // ---- mask ----
#pragma unroll
    for (int nt = 0; nt < 4; ++nt) {
      int kidx = kv + nt * 16 + c;
      int mk = kt.mk[nt];
      float apen = mk ? 0.f : NEGV;
      float bpen = mk ? NEGV : 0.f;
#pragma unroll
      for (int i = 0; i < 4; ++i) {
        float pen = mq[i] ? ((kidx > qi[i]) ? NEGV : apen) : bpen;
        sc[nt][i] += pen;
      }
    }
    // ---- online softmax ----
    float tm[4], al[4], rs[4];
#pragma unroll
    for (int i = 0; i < 4; ++i)
      tm[i] = fmaxf(fmaxf(sc[0][i], sc[1][i]), fmaxf(sc[2][i], sc[3][i]));
#pragma unroll
    for (int d = 1; d < 16; d <<= 1)
#pragma unroll
      for (int i = 0; i < 4; ++i) tm[i] = fmaxf(tm[i], __shfl_xor(tm[i], d));
#pragma unroll
    for (int i = 0; i < 4; ++i) {
      float mn = fmaxf(mi[i], tm[i]);
      al[i] = __expf(mi[i] - mn);
      mi[i] = mn;
      rs[i] = 0.f;
    }
#pragma unroll
    for (int nt = 0; nt < 4; ++nt)
#pragma unroll
      for (int i = 0; i < 4; ++i) {
        float p = __expf(sc[nt][i] - mi[i]);
        sc[nt][i] = p;
        rs[i] += p;
      }
#pragma unroll
    for (int d = 1; d < 16; d <<= 1)
#pragma unroll
      for (int i = 0; i < 4; ++i) rs[i] += __shfl_xor(rs[i], d);
#pragma unroll
    for (int i = 0; i < 4; ++i) li[i] = li[i] * al[i] + rs[i];
#pragma unroll
    for (int ht = 0; ht < 4; ++ht)
#pragma unroll
      for (int i = 0; i < 4; ++i) o[ht][i] *= al[i];

    // ---- P -> LDS transpose ----
#pragma unroll
    for (int nt = 0; nt < 4; ++nt)
#pragma unroll
      for (int i = 0; i < 4; ++i) plds[w][g * 4 + i][nt * 16 + c] = f2bfu(sc[nt][i]);
    asm volatile("s_waitcnt lgkmcnt(0)" ::: "memory");
    bf16x8 pa0 = *reinterpret_cast<const bf16x8*>(&plds[w][c][g * 8]);
    bf16x8 pa1 = *reinterpret_cast<const bf16x8*>(&plds[w][c][32 + g * 8]);

    // ---- PV ----
    __builtin_amdgcn_s_setprio(1);
#pragma unroll
    for (int ht = 0; ht < 4; ++ht) {
      o[ht] = mfma16(pa0, v0[ht], o[ht]);
      o[ht] = mfma16(pa1, v1[ht], o[ht]);
    }
    __builtin_amdgcn_s_setprio(0);
  };

  KT kt;
  bf16x8 v0[4], v1[4];
  loadK(kvbeg, kt);
  loadV(kvbeg, v0, v1);
  for (int kv = kvbeg; kv < kvend - 64; kv += 64) {
    KT ktn;
    bf16x8 w0[4], w1[4];
    loadK(kv + 64, ktn);
    loadV(kv + 64, w0, w1);
    body(kv, kt, v0, v1);
#pragma unroll
    for (int j = 0; j < 4; ++j) {
      kt.a0[j] = ktn.a0[j]; kt.a1[j] = ktn.a1[j]; kt.mk[j] = ktn.mk[j];
      v0[j] = w0[j]; v1[j] = w1[j];
    }
  }
  body(kvend - 64, kt, v0, v1);

  // ---- combine the 4 KV-split partials ----
  if (c == 0) {
#pragma unroll
    for (int i = 0; i < 4; ++i) {
      mb[w][g * 4 + i] = mi[i];
      lb[w][g * 4 + i] = li[i];
    }
  }
#pragma unroll
  for (int ht = 0; ht < 4; ++ht)
#pragma unroll
    for (int i = 0; i < 4; ++i) obuf[w][g * 4 + i][ht * 16 + c] = o[ht][i];
  __syncthreads();

  int row = t >> 4, hq = t & 15;
  float mg = fmaxf(fmaxf(mb[0][row], mb[1][row]), fmaxf(mb[2][row], mb[3][row]));
  float lg = 0.f, sw[4];
#pragma unroll
  for (int w2 = 0; w2 < 4; ++w2) {
    sw[w2] = __expf(mb[w2][row] - mg);
    lg += lb[w2][row] * sw[w2];
  }
  float4 ov = {0.f, 0.f, 0.f, 0.f};
#pragma unroll
  for (int w2 = 0; w2 < 4; ++w2) {
    float4 ob = *reinterpret_cast<const float4*>(&obuf[w2][row][hq * 4]);
    ov.x += ob.x * sw[w2]; ov.y += ob.y * sw[w2];
    ov.z += ob.z * sw[w2]; ov.w += ob.w * sw[w2];
  }
  float inv = 1.f / lg;
  float4 res = {ov.x * inv, ov.y * inv, ov.z * inv, ov.w * inv};
  *reinterpret_cast<float4*>(out + ((size_t)(b * Ss + q0 + row)) * Hh + hq * 4) = res;
}

extern "C" void kernel_launch(void* const* d_in, const int* in_sizes, int n_in,
                              void* d_out, int out_size, void* d_ws, size_t ws_size,
                              hipStream_t stream) {
  const float* hs = (const float*)d_in[0];
  const int* am = (const int*)d_in[1];
  const float* Wq = (const float*)d_in[2];
  const float* bq = (const float*)d_in[3];
  const float* Wk = (const float*)d_in[4];
  const float* bk = (const float*)d_in[5];
  const float* Wv = (const float*)d_in[6];
  const float* bv = (const float*)d_in[7];
  float* out = (float*)d_out;

  char* ws = (char*)d_ws;
  ushort_t* qsp = (ushort_t*)(ws + 0);                // 2 MB: [B*S][64] bf16, pre-scaled
  ushort_t* kp = (ushort_t*)(ws + (2u << 20));        // 2 MB: [B*S][64] bf16
  ushort_t* vtp = (ushort_t*)(ws + (4u << 20));       // 2 MB: [B][64][S] bf16 (V^T)
  ushort_t* wtp = (ushort_t*)(ws + (6u << 20));       // 384 KB: [3][64][1024] bf16 (W^T)

  k_wtrans<<<dim3(16, 3), 256, 0, stream>>>(Wq, Wk, Wv, wtp);
  k_proj<<<dim3(1024), 256, 0, stream>>>(hs, bq, bk, bv, wtp, qsp, kp, vtp);
  k_attn<<<dim3(128, 8), 256, 0, stream>>>(qsp, kp, vtp, am, out);
}

// Round 4
// 116.004 us; speedup vs baseline: 1.1836x; 1.0739x over previous
//
#include <hip/hip_runtime.h>

typedef float f32x4 __attribute__((ext_vector_type(4)));
typedef float f32x16 __attribute__((ext_vector_type(16)));
typedef unsigned int u32x4 __attribute__((ext_vector_type(4)));
typedef __bf16 bf16x8 __attribute__((ext_vector_type(8)));
typedef unsigned short ushort_t;

#define NEG2 (-144269.5f)   /* -1e5 * log2(e) */
#define SCLQ (0.18033688f)  /* 0.125 * log2(e) */
#define THR2 (11.5f)        /* defer-max threshold, ~8 nats in bits */

constexpr int Ss = 2048, Ee = 1024, Hh = 64;

static __device__ __forceinline__ ushort_t f2bfu(float f) {
  return __builtin_bit_cast(ushort_t, (__bf16)f);
}
static __device__ __forceinline__ f32x4 mfma16(bf16x8 a, bf16x8 b, f32x4 c) {
  return __builtin_amdgcn_mfma_f32_16x16x32_bf16(a, b, c, 0, 0, 0);
}
static __device__ __forceinline__ f32x16 mfma32(bf16x8 a, bf16x8 b, f32x16 c) {
  return __builtin_amdgcn_mfma_f32_32x32x16_bf16(a, b, c, 0, 0, 0);
}
static __device__ __forceinline__ unsigned cvtpk(float a, float b) {
  unsigned r;
  asm("v_cvt_pk_bf16_f32 %0, %1, %2" : "=v"(r) : "v"(a), "v"(b));
  return r;
}
// NOTE: only call with a,b holding DIFFERENT values. With identical values the
// compiler ties both "+v" operands to one physical reg -> v_permlane32_swap v5,v5
// which in-place cross-swaps (the R3 bug). Cross-half reductions use __shfl_xor.
static __device__ __forceinline__ void swap32(unsigned& a, unsigned& b) {
  asm("v_permlane32_swap_b32 %0, %1" : "+v"(a), "+v"(b));
}

// ---------------- weight transpose + bf16 convert: Wt[m][h][e] ----------------
__global__ __launch_bounds__(256) void k_wtrans(const float* __restrict__ Wq,
                                                const float* __restrict__ Wk,
                                                const float* __restrict__ Wv,
                                                ushort_t* __restrict__ Wt) {
  __shared__ float tile[64][65];
  const float* W = (blockIdx.y == 0) ? Wq : (blockIdx.y == 1 ? Wk : Wv);
  int kt = blockIdx.x, t = threadIdx.x;
  int r = t >> 2, cq = t & 3;
  const float* src = W + (kt * 64 + r) * Hh + cq * 16;
#pragma unroll
  for (int j = 0; j < 16; j += 4) {
    float4 v = *reinterpret_cast<const float4*>(src + j);
    tile[r][cq * 16 + j + 0] = v.x;
    tile[r][cq * 16 + j + 1] = v.y;
    tile[r][cq * 16 + j + 2] = v.z;
    tile[r][cq * 16 + j + 3] = v.w;
  }
  __syncthreads();
  int n = t >> 2, kq = t & 3;
  ushort_t ob[16];
#pragma unroll
  for (int j = 0; j < 16; ++j) ob[j] = f2bfu(tile[kq * 16 + j][n]);
  ushort_t* dst = Wt + ((size_t)blockIdx.y * 64 + n) * Ee + kt * 64 + kq * 16;
  reinterpret_cast<uint4*>(dst)[0] = reinterpret_cast<uint4*>(ob)[0];
  reinterpret_cast<uint4*>(dst)[1] = reinterpret_cast<uint4*>(ob)[1];
}

// ---------------- fused QKV projection: 256 blocks x 8 waves x 64 rows ----------------
// wave w: row-tile wr = w&3 (16 rows), col-half wc = w>>2 (96 of 192 output cols).
// q stored [B*S][64] bf16 PRE-SCALED by 0.125*log2e; k [B*S][64]; v transposed vt[b][h][s].
// Also emits pen[b][2][S] f32: penA (active-q xor term), penP (pad-q term).
__global__ __launch_bounds__(512) void k_proj(const float* __restrict__ hs,
                                              const float* __restrict__ bq,
                                              const float* __restrict__ bk,
                                              const float* __restrict__ bv,
                                              const ushort_t* __restrict__ Wt,
                                              const int* __restrict__ am,
                                              ushort_t* __restrict__ q,
                                              ushort_t* __restrict__ k,
                                              ushort_t* __restrict__ vt,
                                              float* __restrict__ pen) {
  int t = threadIdx.x, w = t >> 6, l = t & 63, g = l >> 4, c = l & 15;
  int wr = w & 3, wc = w >> 2;
  int row0 = blockIdx.x * 64;
  const float* ap = hs + (size_t)(row0 + wr * 16 + c) * Ee + g * 8;

  f32x4 acc[6];
#pragma unroll
  for (int nt = 0; nt < 6; ++nt) acc[nt] = f32x4{0.f, 0.f, 0.f, 0.f};

  for (int kk = 0; kk < Ee; kk += 64) {
    bf16x8 af[2];
#pragma unroll
    for (int ks = 0; ks < 2; ++ks) {
      float4 f0 = *reinterpret_cast<const float4*>(ap + kk + ks * 32);
      float4 f1 = *reinterpret_cast<const float4*>(ap + kk + ks * 32 + 4);
      bf16x8 a;
      a[0] = (__bf16)f0.x; a[1] = (__bf16)f0.y; a[2] = (__bf16)f0.z; a[3] = (__bf16)f0.w;
      a[4] = (__bf16)f1.x; a[5] = (__bf16)f1.y; a[6] = (__bf16)f1.z; a[7] = (__bf16)f1.w;
      af[ks] = a;
    }
#pragma unroll
    for (int nt = 0; nt < 6; ++nt) {
      const ushort_t* wp = Wt + (size_t)(wc * 96 + nt * 16 + c) * Ee + kk + g * 8;
      bf16x8 b0 = *reinterpret_cast<const bf16x8*>(wp);
      bf16x8 b1 = *reinterpret_cast<const bf16x8*>(wp + 32);
      acc[nt] = mfma16(af[0], b0, acc[nt]);
      acc[nt] = mfma16(af[1], b1, acc[nt]);
    }
  }

#pragma unroll
  for (int nt = 0; nt < 6; ++nt) {
    int T = wc * 6 + nt;
    int m = T >> 2;
    int h = (T & 3) * 16 + c;
    const float* bias = (m == 0) ? bq : ((m == 1) ? bk : bv);
    float bb = bias[h];
#pragma unroll
    for (int i = 0; i < 4; ++i) {
      int row = row0 + wr * 16 + g * 4 + i;
      float val = acc[nt][i] + bb;
      if (m == 0) {
        q[(size_t)row * Hh + h] = f2bfu(val * SCLQ);
      } else if (m == 1) {
        k[(size_t)row * Hh + h] = f2bfu(val);
      } else {
        int bi = row >> 11, s2 = row & 2047;
        vt[((size_t)(bi * 64 + h)) * Ss + s2] = f2bfu(val);
      }
    }
  }

  if (t < 64) {
    int grow = row0 + t;
    int bi = grow >> 11, s2 = grow & 2047;
    int mv = am[grow];
    pen[((size_t)bi * 2 + 0) * Ss + s2] = mv ? 0.f : NEG2;
    pen[((size_t)bi * 2 + 1) * Ss + s2] = mv ? NEG2 : 0.f;
  }
}

// ---------------- fused masked flash attention, swapped-QK 32x32, in-register softmax ----
// Block: 32 q-rows of one batch, 4 waves split keys (512 each, 16 tiles of 32).
// Lane owns one q-row (lo = l&31): softmax = 15 in-lane max/sum + 1 cross-half shfl.
// P -> PV A-frags via 8 cvt_pk + 4 permlane32_swap. Defer-max (T13) makes O-rescale rare.
__global__ __launch_bounds__(256) void k_attn(const ushort_t* __restrict__ qs,
                                              const ushort_t* __restrict__ km,
                                              const ushort_t* __restrict__ vt,
                                              const int* __restrict__ am,
                                              const float* __restrict__ pen,
                                              float* __restrict__ out) {
  __shared__ float obuf[4][32][64];
  __shared__ float mls[4][32], lls[4][32];

  int t = threadIdx.x, w = t >> 6, l = t & 63, lo = l & 31, hi = l >> 5;
  int b = blockIdx.y, q0 = blockIdx.x * 32;

  // Q B-frags (hoisted): lane holds Q[q0+lo][c*16 + hi*8 + j]
  const ushort_t* qp = qs + ((size_t)(b * Ss + q0 + lo)) * Hh + hi * 8;
  bf16x8 qf[4];
#pragma unroll
  for (int c = 0; c < 4; ++c) qf[c] = *reinterpret_cast<const bf16x8*>(qp + c * 16);

  int mq = am[b * Ss + q0 + lo];
  float negq = mq ? NEG2 : 0.f;
  const float* psel = pen + ((size_t)b * 2 + (mq ? 0 : 1)) * Ss;

  float m = -3.0e38f, ll = 0.f;
  f32x16 o0 = {0.f, 0.f, 0.f, 0.f, 0.f, 0.f, 0.f, 0.f, 0.f, 0.f, 0.f, 0.f, 0.f, 0.f, 0.f, 0.f};
  f32x16 o1 = o0;
  const f32x16 z16 = o0;

  const int kvbeg = w * 512;
  for (int it = 0; it < 16; ++it) {
    int kv0 = kvbeg + it * 32;

    // K A-frags: lane holds K[kv0+lo][c*16 + hi*8 + j]
    const ushort_t* kp = km + ((size_t)(b * Ss + kv0 + lo)) * Hh + hi * 8;
    bf16x8 kf0 = *reinterpret_cast<const bf16x8*>(kp);
    bf16x8 kf1 = *reinterpret_cast<const bf16x8*>(kp + 16);
    bf16x8 kf2 = *reinterpret_cast<const bf16x8*>(kp + 32);
    bf16x8 kf3 = *reinterpret_cast<const bf16x8*>(kp + 48);

    // V B-frags: lane holds V[kv0 + c2*16 + hi*8 + j][dt*32 + lo] from vt[b][d][s]
    const ushort_t* vp0 = vt + ((size_t)(b * 64 + lo)) * Ss + kv0 + hi * 8;
    const ushort_t* vp1 = vt + ((size_t)(b * 64 + 32 + lo)) * Ss + kv0 + hi * 8;
    bf16x8 vf00 = *reinterpret_cast<const bf16x8*>(vp0);
    bf16x8 vf10 = *reinterpret_cast<const bf16x8*>(vp0 + 16);
    bf16x8 vf01 = *reinterpret_cast<const bf16x8*>(vp1);
    bf16x8 vf11 = *reinterpret_cast<const bf16x8*>(vp1 + 16);

    // penalty vectors: reg r -> key kv0 + (r&3) + 8*(r>>2) + 4*hi
    f32x4 pv[4];
#pragma unroll
    for (int j = 0; j < 4; ++j)
      pv[j] = *reinterpret_cast<const f32x4*>(psel + kv0 + j * 8 + hi * 4);

    // ---- scores: D[key][q], key = (r&3)+8*(r>>2)+4*hi, q = lo ----
    f32x16 sc = mfma32(kf0, qf[0], z16);
    sc = mfma32(kf1, qf[1], sc);
    sc = mfma32(kf2, qf[2], sc);
    sc = mfma32(kf3, qf[3], sc);

    if (kv0 == q0) {  // straddle tile: per-reg causal
#pragma unroll
      for (int r = 0; r < 16; ++r) {
        int kr = (r & 3) + 8 * (r >> 2) + 4 * hi;
        float pc = (kr > lo) ? negq : 0.f;
        sc[r] += pv[r >> 2][r & 3] + pc;
      }
    } else {
      float addt = (kv0 > q0) ? negq : 0.f;
#pragma unroll
      for (int r = 0; r < 16; ++r) sc[r] += pv[r >> 2][r & 3] + addt;
    }

    // ---- row max (in-lane tree + cross-half shfl) ----
    float pm01 = fmaxf(sc[0], sc[1]), pm23 = fmaxf(sc[2], sc[3]);
    float pm45 = fmaxf(sc[4], sc[5]), pm67 = fmaxf(sc[6], sc[7]);
    float pm89 = fmaxf(sc[8], sc[9]), pmab = fmaxf(sc[10], sc[11]);
    float pmcd = fmaxf(sc[12], sc[13]), pmef = fmaxf(sc[14], sc[15]);
    float pm = fmaxf(fmaxf(fmaxf(pm01, pm23), fmaxf(pm45, pm67)),
                     fmaxf(fmaxf(pm89, pmab), fmaxf(pmcd, pmef)));
    pm = fmaxf(pm, __shfl_xor(pm, 32));

    // ---- defer-max: rescale only when the running max grows past THR2 ----
    if (!__all(pm <= m + THR2)) {
      float mn = fmaxf(m, pm);
      float alpha = __builtin_amdgcn_exp2f(m - mn);
      m = mn;
      ll *= alpha;
      int ia = __builtin_bit_cast(int, alpha);
#pragma unroll
      for (int r = 0; r < 16; ++r) {
        int qrow = (r & 3) + 8 * (r >> 2) + 4 * hi;
        float af = __builtin_bit_cast(float, __builtin_amdgcn_ds_bpermute(qrow << 2, ia));
        o0[r] *= af;
        o1[r] *= af;
      }
    }

    // ---- p = exp2(sc - m), row sum ----
    float p[16];
    float ts = 0.f;
#pragma unroll
    for (int r = 0; r < 16; ++r) {
      p[r] = __builtin_amdgcn_exp2f(sc[r] - m);
      ts += p[r];
    }
    ts += __shfl_xor(ts, 32);
    ll += ts;

    // ---- P -> PV A-frags: 8 cvt_pk + 4 permlane32_swap (distinct values: safe) ----
    unsigned x0 = cvtpk(p[0], p[1]), y0 = cvtpk(p[2], p[3]);
    unsigned z0 = cvtpk(p[4], p[5]), w0 = cvtpk(p[6], p[7]);
    swap32(x0, z0);
    swap32(y0, w0);
    unsigned x1 = cvtpk(p[8], p[9]), y1 = cvtpk(p[10], p[11]);
    unsigned z1 = cvtpk(p[12], p[13]), w1 = cvtpk(p[14], p[15]);
    swap32(x1, z1);
    swap32(y1, w1);
    bf16x8 pa0 = __builtin_bit_cast(bf16x8, u32x4{x0, y0, z0, w0});
    bf16x8 pa1 = __builtin_bit_cast(bf16x8, u32x4{x1, y1, z1, w1});

    // ---- PV: D[q][d] ----
    o0 = mfma32(pa0, vf00, o0);
    o0 = mfma32(pa1, vf10, o0);
    o1 = mfma32(pa0, vf01, o1);
    o1 = mfma32(pa1, vf11, o1);
  }

  // ---- stash partials ----
#pragma unroll
  for (int r = 0; r < 16; ++r) {
    int qrow = (r & 3) + 8 * (r >> 2) + 4 * hi;
    obuf[w][qrow][lo] = o0[r];
    obuf[w][qrow][32 + lo] = o1[r];
  }
  if (hi == 0) {
    mls[w][lo] = m;
    lls[w][lo] = ll;
  }
  __syncthreads();

  // ---- combine 4 KV-split partials: thread -> (qrow = t>>3, 8 d-cols) ----
  int qr = t >> 3, dg = t & 7;
  float mg = fmaxf(fmaxf(mls[0][qr], mls[1][qr]), fmaxf(mls[2][qr], mls[3][qr]));
  float lg = 0.f, sw[4];
#pragma unroll
  for (int ww = 0; ww < 4; ++ww) {
    sw[ww] = __builtin_amdgcn_exp2f(mls[ww][qr] - mg);
    lg += lls[ww][qr] * sw[ww];
  }
  float a8[8] = {0.f, 0.f, 0.f, 0.f, 0.f, 0.f, 0.f, 0.f};
#pragma unroll
  for (int ww = 0; ww < 4; ++ww) {
    float4 c0 = *reinterpret_cast<const float4*>(&obuf[ww][qr][dg * 8]);
    float4 c1 = *reinterpret_cast<const float4*>(&obuf[ww][qr][dg * 8 + 4]);
    a8[0] += c0.x * sw[ww]; a8[1] += c0.y * sw[ww];
    a8[2] += c0.z * sw[ww]; a8[3] += c0.w * sw[ww];
    a8[4] += c1.x * sw[ww]; a8[5] += c1.y * sw[ww];
    a8[6] += c1.z * sw[ww]; a8[7] += c1.w * sw[ww];
  }
  float inv = 1.f / lg;
  float4 r0 = {a8[0] * inv, a8[1] * inv, a8[2] * inv, a8[3] * inv};
  float4 r1 = {a8[4] * inv, a8[5] * inv, a8[6] * inv, a8[7] * inv};
  float* op = out + ((size_t)(b * Ss + q0 + qr)) * Hh + dg * 8;
  *reinterpret_cast<float4*>(op) = r0;
  *reinterpret_cast<float4*>(op + 4) = r1;
}

extern "C" void kernel_launch(void* const* d_in, const int* in_sizes, int n_in,
                              void* d_out, int out_size, void* d_ws, size_t ws_size,
                              hipStream_t stream) {
  const float* hs = (const float*)d_in[0];
  const int* am = (const int*)d_in[1];
  const float* Wq = (const float*)d_in[2];
  const float* bq = (const float*)d_in[3];
  const float* Wk = (const float*)d_in[4];
  const float* bk = (const float*)d_in[5];
  const float* Wv = (const float*)d_in[6];
  const float* bv = (const float*)d_in[7];
  float* out = (float*)d_out;

  char* ws = (char*)d_ws;
  ushort_t* qsp = (ushort_t*)(ws + 0);                  // 2 MB: [B*S][64] bf16, scaled
  ushort_t* kp = (ushort_t*)(ws + (2u << 20));          // 2 MB: [B*S][64] bf16
  ushort_t* vtp = (ushort_t*)(ws + (4u << 20));         // 2 MB: [B][64][S] bf16 (V^T)
  ushort_t* wtp = (ushort_t*)(ws + (6u << 20));         // 384 KB: [3][64][1024] bf16 (W^T)
  float* penp = (float*)(ws + (6u << 20) + (512u << 10));  // 128 KB: [B][2][S] f32

  k_wtrans<<<dim3(16, 3), 256, 0, stream>>>(Wq, Wk, Wv, wtp);
  k_proj<<<dim3(256), 512, 0, stream>>>(hs, bq, bk, bv, wtp, am, qsp, kp, vtp, penp);
  k_attn<<<dim3(64, 8), 256, 0, stream>>>(qsp, kp, vtp, am, penp, out);
}